// Round 1
// baseline (1035.322 us; speedup 1.0000x reference)
//
#include <hip/hip_runtime.h>
#include <hip/hip_bf16.h>
#include <stdint.h>
#include <stdio.h>

// Problem sizes (fixed by setup_inputs)
#define B_ 4
#define S_ 2048
#define D_ 2048
#define P_ 2729
#define NP 2816            // P padded to multiple of 128
#define M_ (B_ * S_)       // 8192

// GEMM tile config (m97 structure: 128x128 tile, BK=32, 4 waves)
#define BM 128
#define BN 128
#define BK 32

typedef __attribute__((ext_vector_type(8))) short bh8;   // 8 x bf16 (4 VGPRs)
typedef __attribute__((ext_vector_type(4))) float fx4;   // MFMA accumulator

static __device__ __forceinline__ float bf2f(unsigned short u) {
  union { unsigned int i; float f; } c;
  c.i = ((unsigned int)u) << 16;
  return c.f;
}
static __device__ __forceinline__ unsigned short f2bf(float f) {
  union { __hip_bfloat16 h; unsigned short u; } c;
  c.h = __float2bfloat16(f);
  return c.u;
}
static __device__ __forceinline__ float fast_tanh(float x) {
  // tanh(x) = 1 - 2/(exp(2x)+1); correct saturation at +/-inf
  return 1.0f - 2.0f / (__expf(2.0f * x) + 1.0f);
}
static __device__ __forceinline__ float gate_act(float z) {
  // sigmoid(15*tanh(z/15))
  float sc = 15.0f * fast_tanh(z * (1.0f / 15.0f));
  return 1.0f / (1.0f + __expf(-sc));
}

static __device__ __forceinline__ void gload_lds16(const __hip_bfloat16* g, __hip_bfloat16* l) {
  __builtin_amdgcn_global_load_lds(
      (const __attribute__((address_space(1))) unsigned int*)g,
      (__attribute__((address_space(3))) unsigned int*)l, 16, 0, 0);
}

// ---------------- RMSNorm + bf16 cast ----------------
__global__ __launch_bounds__(256) void rmsnorm_kernel(const float* __restrict__ x,
                                                      const float* __restrict__ w,
                                                      __hip_bfloat16* __restrict__ xn) {
  int row = blockIdx.x;
  const float4* xr = (const float4*)(x + (size_t)row * D_);
  int t = threadIdx.x;
  float4 v0 = xr[t];
  float4 v1 = xr[t + 256];
  float ss = v0.x * v0.x + v0.y * v0.y + v0.z * v0.z + v0.w * v0.w +
             v1.x * v1.x + v1.y * v1.y + v1.z * v1.z + v1.w * v1.w;
#pragma unroll
  for (int off = 32; off > 0; off >>= 1) ss += __shfl_down(ss, off);
  __shared__ float red[4];
  if ((t & 63) == 0) red[t >> 6] = ss;
  __syncthreads();
  float scale = rsqrtf((red[0] + red[1] + red[2] + red[3]) * (1.0f / (float)D_) + 1e-6f);
  const float4* wp = (const float4*)w;
  float4 w0 = wp[t], w1 = wp[t + 256];
  ushort4 o0, o1;
  o0.x = f2bf(v0.x * scale * w0.x);
  o0.y = f2bf(v0.y * scale * w0.y);
  o0.z = f2bf(v0.z * scale * w0.z);
  o0.w = f2bf(v0.w * scale * w0.w);
  o1.x = f2bf(v1.x * scale * w1.x);
  o1.y = f2bf(v1.y * scale * w1.y);
  o1.z = f2bf(v1.z * scale * w1.z);
  o1.w = f2bf(v1.w * scale * w1.w);
  ushort4* xo = (ushort4*)(xn + (size_t)row * D_);
  xo[t] = o0;
  xo[t + 256] = o1;
}

// ---------------- weight conversion ----------------
// Gate weights: (P_, D_) f32 -> [NP][D_] bf16, zero-padded rows
__global__ __launch_bounds__(256) void convert_gate_w(const float* __restrict__ Wi,
                                                      const float* __restrict__ Wf,
                                                      const float* __restrict__ Wo,
                                                      const float* __restrict__ Wc,
                                                      __hip_bfloat16* __restrict__ Wb) {
  int g = blockIdx.z;
  const float* W = (g == 0) ? Wi : (g == 1) ? Wf : (g == 2) ? Wo : Wc;
  size_t u = (size_t)blockIdx.x * 256 + threadIdx.x;  // float4 index, NP*512 per gate
  int j = (int)(u >> 9);        // row 0..NP-1
  int q = (int)(u & 511);       // float4 within row
  ushort4 o;
  if (j < P_) {
    float4 v = ((const float4*)(W + (size_t)j * D_))[q];
    o.x = f2bf(v.x); o.y = f2bf(v.y); o.z = f2bf(v.z); o.w = f2bf(v.w);
  } else {
    o.x = 0; o.y = 0; o.z = 0; o.w = 0;
  }
  ushort4* dst = (ushort4*)(Wb + (size_t)g * NP * D_ + (size_t)j * D_ + (size_t)q * 4);
  *dst = o;
}

// Wout: (D_, P_) f32 -> [D_][NP] bf16, zero-padded cols (scalar: rows not 16B aligned)
__global__ __launch_bounds__(256) void convert_wout(const float* __restrict__ Wout,
                                                    __hip_bfloat16* __restrict__ Woutb) {
  size_t u = (size_t)blockIdx.x * 256 + threadIdx.x;
  if (u >= (size_t)D_ * NP) return;
  int d = (int)(u / NP);
  int p = (int)(u - (size_t)d * NP);
  float v = (p < P_) ? Wout[(size_t)d * P_ + p] : 0.0f;
  Woutb[u] = __float2bfloat16(v);
}

// ---------------- GEMM core (C = A * B^T), bf16, m97 structure ----------------
// A: [M][LD] row-major, B: [N][LD] row-major (K contiguous both). LD == K stride.
template <int LD, int KTOT>
static __device__ __forceinline__ void gemm_core(const __hip_bfloat16* __restrict__ A,
                                                 const __hip_bfloat16* __restrict__ Bm,
                                                 int tile_m, int tile_n,
                                                 __hip_bfloat16* lA, __hip_bfloat16* lB,
                                                 fx4 (&acc)[4][4]) {
  int t = threadIdx.x;
  int lane = t & 63;
  int w = t >> 6;
  int wr = w >> 1, wc = w & 1;

  // staging: two 16B issues per thread per tile; elem offset in tile = q*2048 + t*8
  int e0 = t * 8;
  int e1 = 2048 + t * 8;
  const __hip_bfloat16* gA0 = A + (size_t)(tile_m + (e0 >> 5)) * LD + (e0 & 31);
  const __hip_bfloat16* gA1 = A + (size_t)(tile_m + (e1 >> 5)) * LD + (e1 & 31);
  const __hip_bfloat16* gB0 = Bm + (size_t)(tile_n + (e0 >> 5)) * LD + (e0 & 31);
  const __hip_bfloat16* gB1 = Bm + (size_t)(tile_n + (e1 >> 5)) * LD + (e1 & 31);

  int frow = lane & 15;
  int fcol = (lane >> 4) * 8;

  for (int k0 = 0; k0 < KTOT; k0 += BK) {
    gload_lds16(gA0 + k0, lA + e0);
    gload_lds16(gA1 + k0, lA + e1);
    gload_lds16(gB0 + k0, lB + e0);
    gload_lds16(gB1 + k0, lB + e1);
    __syncthreads();  // drains vmcnt -> LDS valid
    bh8 af[4], bfr[4];
#pragma unroll
    for (int mf = 0; mf < 4; ++mf)
      af[mf] = *(const bh8*)(lA + (size_t)(wr * 64 + mf * 16 + frow) * BK + fcol);
#pragma unroll
    for (int nf = 0; nf < 4; ++nf)
      bfr[nf] = *(const bh8*)(lB + (size_t)(wc * 64 + nf * 16 + frow) * BK + fcol);
#pragma unroll
    for (int mf = 0; mf < 4; ++mf)
#pragma unroll
      for (int nf = 0; nf < 4; ++nf)
        acc[mf][nf] = __builtin_amdgcn_mfma_f32_16x16x32_bf16(af[mf], bfr[nf], acc[mf][nf], 0, 0, 0);
    __syncthreads();  // all waves done reading before next stage overwrites
  }
}

// Gate GEMM: gates[g][m][n] = act(sum_d xn[m][d] * Wb[g][n][d])
__global__ __launch_bounds__(256) void gemm_gates(const __hip_bfloat16* __restrict__ A,
                                                  const __hip_bfloat16* __restrict__ Wb,
                                                  __hip_bfloat16* __restrict__ G) {
  int gate = blockIdx.z;
  const __hip_bfloat16* Bm = Wb + (size_t)gate * NP * D_;
  __hip_bfloat16* Gg = G + (size_t)gate * M_ * NP;
  int tile_n = blockIdx.x * BN;
  int tile_m = blockIdx.y * BM;

  __shared__ __hip_bfloat16 lA[BM * BK];
  __shared__ __hip_bfloat16 lB[BN * BK];

  fx4 acc[4][4];
#pragma unroll
  for (int i = 0; i < 4; ++i)
#pragma unroll
    for (int j = 0; j < 4; ++j) acc[i][j] = (fx4){0.f, 0.f, 0.f, 0.f};

  gemm_core<D_, D_>(A, Bm, tile_m, tile_n, lA, lB, acc);

  int lane = threadIdx.x & 63;
  int w = threadIdx.x >> 6;
  int wr = w >> 1, wc = w & 1;
#pragma unroll
  for (int mf = 0; mf < 4; ++mf) {
    int mbase = tile_m + wr * 64 + mf * 16 + ((lane >> 4) << 2);
#pragma unroll
    for (int nf = 0; nf < 4; ++nf) {
      int n = tile_n + wc * 64 + nf * 16 + (lane & 15);
      bool valid = (n < P_);
#pragma unroll
      for (int r = 0; r < 4; ++r) {
        float z = acc[mf][nf][r];
        float val = (gate == 3) ? fast_tanh(z) : gate_act(z);
        if (!valid) val = 0.0f;
        Gg[(size_t)(mbase + r) * NP + n] = __float2bfloat16(val);
      }
    }
  }
}

// Output GEMM: out[m][n] = x[m][n] + sum_p outbuf[m][p] * Woutb[n][p]
__global__ __launch_bounds__(256) void gemm_out(const __hip_bfloat16* __restrict__ A,
                                                const __hip_bfloat16* __restrict__ Bw,
                                                const float* __restrict__ X,
                                                float* __restrict__ Out) {
  int tile_n = blockIdx.x * BN;
  int tile_m = blockIdx.y * BM;

  __shared__ __hip_bfloat16 lA[BM * BK];
  __shared__ __hip_bfloat16 lB[BN * BK];

  fx4 acc[4][4];
#pragma unroll
  for (int i = 0; i < 4; ++i)
#pragma unroll
    for (int j = 0; j < 4; ++j) acc[i][j] = (fx4){0.f, 0.f, 0.f, 0.f};

  gemm_core<NP, NP>(A, Bw, tile_m, tile_n, lA, lB, acc);

  int lane = threadIdx.x & 63;
  int w = threadIdx.x >> 6;
  int wr = w >> 1, wc = w & 1;
#pragma unroll
  for (int mf = 0; mf < 4; ++mf) {
    int mbase = tile_m + wr * 64 + mf * 16 + ((lane >> 4) << 2);
#pragma unroll
    for (int nf = 0; nf < 4; ++nf) {
      int n = tile_n + wc * 64 + nf * 16 + (lane & 15);
#pragma unroll
      for (int r = 0; r < 4; ++r) {
        size_t o = (size_t)(mbase + r) * D_ + n;
        Out[o] = X[o] + acc[mf][nf][r];
      }
    }
  }
}

// ---------------- LSTM scan over S ----------------
// One thread per (b, p). Gates pre-activated: i,f,o = sigmoid(softcap(z)), c = tanh(z).
__global__ __launch_bounds__(64) void scan_kernel(const __hip_bfloat16* __restrict__ G,
                                                  const float* __restrict__ h0,
                                                  __hip_bfloat16* __restrict__ outbuf,
                                                  float* __restrict__ hfin) {
  int idx = blockIdx.x * 64 + threadIdx.x;
  if (idx >= B_ * NP) return;
  int b = idx / NP;
  int p = idx - b * NP;
  size_t base = ((size_t)b * S_) * NP + p;
  const unsigned short* gi = (const unsigned short*)G + base;
  const size_t gs = (size_t)M_ * NP;
  const unsigned short* gf = gi + gs;
  const unsigned short* go = gf + gs;
  const unsigned short* gc = go + gs;
  unsigned short* ob = (unsigned short*)outbuf + base;
  float h = (p < P_) ? h0[b * P_ + p] : 0.0f;

  const int U = 8;
  unsigned short pi[U], pf[U], po[U], pc[U];
#pragma unroll
  for (int j = 0; j < U; ++j) {
    size_t off = (size_t)j * NP;
    pi[j] = gi[off]; pf[j] = gf[off]; po[j] = go[off]; pc[j] = gc[off];
  }
  for (int s0 = 0; s0 < S_; s0 += U) {
    unsigned short ci[U], cf[U], co[U], cc[U];
#pragma unroll
    for (int j = 0; j < U; ++j) { ci[j] = pi[j]; cf[j] = pf[j]; co[j] = po[j]; cc[j] = pc[j]; }
    if (s0 + U < S_) {
      size_t nb = (size_t)(s0 + U) * NP;
#pragma unroll
      for (int j = 0; j < U; ++j) {
        size_t off = nb + (size_t)j * NP;
        pi[j] = gi[off]; pf[j] = gf[off]; po[j] = go[off]; pc[j] = gc[off];
      }
    }
#pragma unroll
    for (int j = 0; j < U; ++j) {
      float u_ = bf2f(ci[j]) * bf2f(cc[j]);     // i * tanh(c)
      h = bf2f(cf[j]) * h + u_;                 // h = f*h + u
      float outv = bf2f(co[j]) * fast_tanh(h);  // o * tanh(h)
      ob[(size_t)(s0 + j) * NP] = f2bf(outv);
    }
  }
  if (p < P_) hfin[b * P_ + p] = h;
}

// ---------------- launch ----------------
extern "C" void kernel_launch(void* const* d_in, const int* in_sizes, int n_in,
                              void* d_out, int out_size, void* d_ws, size_t ws_size,
                              hipStream_t stream) {
  const float* x    = (const float*)d_in[0];
  const float* h0   = (const float*)d_in[1];
  const float* Wi   = (const float*)d_in[2];
  const float* Wf   = (const float*)d_in[3];
  const float* Wo   = (const float*)d_in[4];
  const float* Wc   = (const float*)d_in[5];
  const float* Wout = (const float*)d_in[6];
  const float* lnw  = (const float*)d_in[7];
  float* out  = (float*)d_out;
  float* hfin = out + (size_t)M_ * D_;

  // workspace layout (elements of bf16):
  //   phase 1: xn [0, 16.78M), Wb [16.78M, 39.85M), gates [39.85M, 132.1M)
  //   phase 2 (after gate GEMM): outbuf [0, 23.07M), Woutb [23.07M, 28.8M)  (aliases xn/Wb)
  const size_t xn_off    = 0;
  const size_t wb_off    = (size_t)M_ * D_;                    // 16,777,216
  const size_t gates_off = wb_off + (size_t)4 * NP * D_;       // 39,845,888
  const size_t need = (gates_off + (size_t)4 * M_ * NP) * 2;   // bytes
  if (ws_size < need) {
    fprintf(stderr, "kernel_launch: ws too small (%zu < %zu)\n", ws_size, need);
    return;
  }
  __hip_bfloat16* ws     = (__hip_bfloat16*)d_ws;
  __hip_bfloat16* xn     = ws + xn_off;
  __hip_bfloat16* Wb     = ws + wb_off;
  __hip_bfloat16* Gg     = ws + gates_off;
  __hip_bfloat16* outbuf = ws;                                  // aliases xn+Wb (dead)
  __hip_bfloat16* Woutb  = ws + (size_t)M_ * NP;                // aliases Wb (dead)

  convert_gate_w<<<dim3(NP * 512 / 256, 1, 4), 256, 0, stream>>>(Wi, Wf, Wo, Wc, Wb);
  rmsnorm_kernel<<<M_, 256, 0, stream>>>(x, lnw, xn);
  gemm_gates<<<dim3(NP / BN, M_ / BM, 4), 256, 0, stream>>>(xn, Wb, Gg);
  convert_wout<<<(int)(((size_t)D_ * NP + 255) / 256), 256, 0, stream>>>(Wout, Woutb);
  scan_kernel<<<(B_ * NP) / 64, 64, 0, stream>>>(Gg, h0, outbuf, hfin);
  gemm_out<<<dim3(D_ / BN, M_ / BM), 256, 0, stream>>>(outbuf, Woutb, x, out);
}